// Round 2
// baseline (855.633 us; speedup 1.0000x reference)
//
#include <hip/hip_runtime.h>
#include <hip/hip_bf16.h>

// VQ codebook lookup: z_e (16,256,32,32) f32, codebook (8192,256) f32.
// Outputs concatenated f32: z_q_st (4194304) | loss (1) | codes (16384).
// n = b*1024 + hw;  z_flat[n][d] = z_e[b*262144 + d*1024 + hw]
//
// Reference semantics replicated exactly:
//   dist = fl32( zz_n - 2*dot_nk )   [ + ||c||^2 is < half-ulp(zz) -> absorbed ]
//   dot_nk = sequential f32 FMA chain over d = 0..255 (matches sgemm microkernels)
//   argmin ties -> lowest index.

#define NT 128          // n rows per block tile
#define KT 128          // codes per k-tile iteration
#define DC 64           // d chunk
#define KS 4            // k splits
#define KRANGE (8192 / KS)
#define ZN_OFF 0                       // ws floats: znorm[16384]
#define PSCORE_OFF 16384               // pscore[KS][16384]
#define PIDX_OFF (16384 + KS*16384)    // pidx[KS][16384]

// ---------------- kernel 1: z row norms (value only needs right binade) ----------------
__global__ __launch_bounds__(256)
void znorm_kernel(const float* __restrict__ z, float* __restrict__ zn) {
    int n = blockIdx.x * 256 + threadIdx.x;
    int b = n >> 10, hw = n & 1023;
    const float* zp = z + (size_t)b * 262144 + hw;
    float s = 0.f;
    for (int d = 0; d < 256; ++d) {
        float v = zp[(size_t)d << 10];
        s += v * v;
    }
    zn[n] = s;
}

// ---------------- kernel 2: fused distance GEMM + argmin ----------------
__global__ __launch_bounds__(256, 2)
void dist_argmin_kernel(const float* __restrict__ z,
                        const float* __restrict__ cb,
                        const float* __restrict__ zn,
                        float* __restrict__ pscore,
                        int* __restrict__ pidx) {
    __shared__ float zs[DC][NT];   // 32 KB, [d][n]
    __shared__ float cs[DC][KT];   // 32 KB, [d][k] (xor-swizzled columns)

    const int tid = threadIdx.x;
    const int tn = tid & 15;       // n group
    const int tk = tid >> 4;       // k group
    const int n0 = blockIdx.x * NT;
    const int b = n0 >> 10;
    const int hw0 = n0 & 1023;
    const float* zb = z + (size_t)b * 262144 + hw0;   // + d*1024 + n
    const int k0base = blockIdx.y * KRANGE;

    // z row norms for this thread's 8 rows
    float zzr[8];
#pragma unroll
    for (int i = 0; i < 8; ++i) {
        int row = (i < 4) ? (tn * 4 + i) : (64 + tn * 4 + (i - 4));
        zzr[i] = zn[n0 + row];
    }

    float best[8];
    int bidx[8];
#pragma unroll
    for (int i = 0; i < 8; ++i) { best[i] = 3.0e38f; bidx[i] = 0; }

    for (int kt = 0; kt < KRANGE / KT; ++kt) {
        const int k0 = k0base + kt * KT;
        float acc[8][8];
#pragma unroll
        for (int i = 0; i < 8; ++i)
#pragma unroll
            for (int j = 0; j < 8; ++j) acc[i][j] = 0.f;

        for (int dc = 0; dc < 256; dc += DC) {
            __syncthreads();   // protect LDS from previous iteration's readers
            // stage z chunk: DC x NT floats, [d][n], coalesced float4
#pragma unroll
            for (int it = 0; it < 8; ++it) {
                int idx = it * 256 + tid;
                int d = idx >> 5;        // 0..63
                int nv = idx & 31;       // float4 col index
                float4 v = *(const float4*)(zb + (size_t)(dc + d) * 1024 + nv * 4);
                *(float4*)&zs[d][nv * 4] = v;
            }
            // stage c chunk with transpose + xor swizzle (bank-conflict-free)
#pragma unroll
            for (int it = 0; it < 8; ++it) {
                int idx = it * 256 + tid;
                int k = idx >> 4;        // 0..127
                int dv = idx & 15;       // d4 group; d = dv*4+j
                float4 v = *(const float4*)(cb + (size_t)(k0 + k) * 256 + dc + dv * 4);
                int colv = k ^ ((dv & 7) << 2);
                cs[dv * 4 + 0][colv] = v.x;
                cs[dv * 4 + 1][colv] = v.y;
                cs[dv * 4 + 2][colv] = v.z;
                cs[dv * 4 + 3][colv] = v.w;
            }
            __syncthreads();
            // compute: 64 FMA per thread per d; d strictly ascending,
            // single accumulator chain per (i,j) -> bitwise matches sgemm
#pragma unroll 2
            for (int d = 0; d < DC; ++d) {
                int swz = ((d >> 2) & 7) << 2;
                float4 a0 = *(const float4*)&zs[d][tn * 4];
                float4 a1 = *(const float4*)&zs[d][64 + tn * 4];
                float4 b0 = *(const float4*)&cs[d][(tk * 4) ^ swz];
                float4 b1 = *(const float4*)&cs[d][(64 + tk * 4) ^ swz];
                float av[8] = {a0.x, a0.y, a0.z, a0.w, a1.x, a1.y, a1.z, a1.w};
                float bv[8] = {b0.x, b0.y, b0.z, b0.w, b1.x, b1.y, b1.z, b1.w};
#pragma unroll
                for (int i = 0; i < 8; ++i)
#pragma unroll
                    for (int j = 0; j < 8; ++j)
                        acc[i][j] = fmaf(av[i], bv[j], acc[i][j]);
            }
        }
        // finalize tile: score = fl32(zz - 2*dot) ; running argmin (k ascending)
        // (2*acc is exact, so fma-contraction of this expression is bit-identical)
#pragma unroll
        for (int j = 0; j < 8; ++j) {
            int kloc = (j < 4) ? (tk * 4 + j) : (64 + tk * 4 + (j - 4));
            int kk = k0 + kloc;
#pragma unroll
            for (int i = 0; i < 8; ++i) {
                float s = zzr[i] - 2.0f * acc[i][j];
                if (s < best[i]) { best[i] = s; bidx[i] = kk; }
            }
        }
    }

    // cross-thread (tk) reduce per n row
    __syncthreads();
    float* sredf = &zs[0][0];        // 128*16 floats
    int* sredi = (int*)&cs[0][0];    // 128*16 ints
#pragma unroll
    for (int i = 0; i < 8; ++i) {
        int row = (i < 4) ? (tn * 4 + i) : (64 + tn * 4 + (i - 4));
        sredf[row * 16 + tk] = best[i];
        sredi[row * 16 + tk] = bidx[i];
    }
    __syncthreads();
    if (tid < NT) {
        float bs = sredf[tid * 16];
        int bi = sredi[tid * 16];
#pragma unroll
        for (int t = 1; t < 16; ++t) {
            float s = sredf[tid * 16 + t];
            int ix = sredi[tid * 16 + t];
            if (s < bs || (s == bs && ix < bi)) { bs = s; bi = ix; }
        }
        pscore[blockIdx.y * 16384 + n0 + tid] = bs;
        pidx[blockIdx.y * 16384 + n0 + tid] = bi;
    }
}

// ---------------- kernel 3: combine splits, emit codes/z_q/loss ----------------
__global__ __launch_bounds__(256)
void finalize_kernel(const float* __restrict__ z, const float* __restrict__ cb,
                     const float* __restrict__ pscore, const int* __restrict__ pidx,
                     float* __restrict__ out) {
    __shared__ int codes_s[64];
    __shared__ float wsum[4];
    const int nbase = blockIdx.x * 64;
    const int tid = threadIdx.x;
    if (tid < 64) {
        int n = nbase + tid;
        float bs = pscore[n];
        int bi = pidx[n];
#pragma unroll
        for (int p = 1; p < KS; ++p) {
            float s = pscore[p * 16384 + n];
            int ix = pidx[p * 16384 + n];
            if (s < bs || (s == bs && ix < bi)) { bs = s; bi = ix; }
        }
        codes_s[tid] = bi;
        out[4194305 + n] = (float)bi;   // codes as f32
    }
    __syncthreads();
    const int lane = tid & 63;
    const int w = tid >> 6;            // 4 waves cover d in chunks of 64
    const int n = nbase + lane;
    const int b = n >> 10, hw = n & 1023;
    const int code = codes_s[lane];
    const float* crow = cb + (size_t)code * 256;
    const float* zrow = z + (size_t)b * 262144 + hw;
    float* orow = out + (size_t)b * 262144 + hw;
    float part = 0.f;
    for (int j = 0; j < 64; ++j) {
        int d = w * 64 + j;
        float c = crow[d];
        float ze = zrow[(size_t)d * 1024];
        orow[(size_t)d * 1024] = c;     // z_q_st forward value == z_q
        float diff = ze - c;
        part += diff * diff;
    }
#pragma unroll
    for (int off = 32; off > 0; off >>= 1) part += __shfl_down(part, off);
    if (lane == 0) wsum[w] = part;
    __syncthreads();
    if (tid == 0) {
        float t = (wsum[0] + wsum[1] + wsum[2] + wsum[3]) * (1.25f / 4194304.f);
        atomicAdd(out + 4194304, t);
    }
}

extern "C" void kernel_launch(void* const* d_in, const int* in_sizes, int n_in,
                              void* d_out, int out_size, void* d_ws, size_t ws_size,
                              hipStream_t stream) {
    const float* z = (const float*)d_in[0];
    const float* cb = (const float*)d_in[1];
    float* out = (float*)d_out;
    float* ws = (float*)d_ws;

    float* zn = ws + ZN_OFF;                 // 16384 f
    float* pscore = ws + PSCORE_OFF;         // KS*16384 f
    int* pidx = (int*)(ws + PIDX_OFF);       // KS*16384 i

    znorm_kernel<<<16384 / 256, 256, 0, stream>>>(z, zn);
    dim3 grid(16384 / NT, KS);
    dist_argmin_kernel<<<grid, 256, 0, stream>>>(z, cb, zn, pscore, pidx);
    hipMemsetAsync(out + 4194304, 0, sizeof(float), stream);  // zero loss slot
    finalize_kernel<<<16384 / 64, 256, 0, stream>>>(z, cb, pscore, pidx, out);
}

// Round 3
// 571.002 us; speedup vs baseline: 1.4985x; 1.4985x over previous
//
#include <hip/hip_runtime.h>

// VQ codebook: z_e (16,256,32,32) f32, codebook (8192,256) f32.
// out f32: z_q_st[4194304] | loss[1] | codes[16384].
// n = b*1024+hw; z_flat[n][d] = z_e[b*262144 + d*1024 + hw]
// Reference: dist = fl32(zz - 2*dot), dot = sequential f32 FMA chain d=0..255,
// argmin ties -> lowest index.  (validated bitwise in round 2)
//
// Strategy: bf16-split MFMA screening GEMM (zh*ch + zh*cl + zl*ch, eps<~4e-7)
// + per-row candidate collection within margin of running global min
// + exact sequential-chain rescore of candidates only.

#define CAP 48

typedef short bf16x8 __attribute__((ext_vector_type(8)));
typedef float f32x4 __attribute__((ext_vector_type(4)));

__device__ __forceinline__ unsigned short f2bf(float f) {
    unsigned u = __float_as_uint(f);
    return (unsigned short)((u + 0x7fffu + ((u >> 16) & 1u)) >> 16);
}
__device__ __forceinline__ float bf2f(unsigned short h) {
    return __uint_as_float(((unsigned)h) << 16);
}
__device__ __forceinline__ float ulpf(float x) {   // 2^(exp(x)-23), x normal positive
    return __uint_as_float((__float_as_uint(x) & 0x7f800000u) - (23u << 23));
}
__device__ __forceinline__ void gload_lds16(const void* g, void* l) {
    __builtin_amdgcn_global_load_lds(
        (const __attribute__((address_space(1))) void*)g,
        (__attribute__((address_space(3))) void*)l, 16, 0, 0);
}

// ---- ws byte layout (new path) ----
#define ZN_B      0u          // f32[16384]
#define CODES_B   65536u      // i32[16384]
#define GMIN_B    131072u     // u32[16384]
#define CNT_B     196608u     // u32[16384]
#define CANDI_B   262144u     // i32[16384*CAP] = 3 MB
#define ZH_B      4194304u    // bf16[16384*256]
#define ZL_B      12582912u
#define CH_B      20971520u   // bf16[8192*256]
#define CL_B      25165824u
#define WS_NEED   29360128u

// ---------------- znorm (shared by both paths) ----------------
__global__ __launch_bounds__(256)
void znorm_kernel(const float* __restrict__ z, float* __restrict__ zn) {
    int n = blockIdx.x * 256 + threadIdx.x;
    int b = n >> 10, hw = n & 1023;
    const float* zp = z + (size_t)b * 262144 + hw;
    float s = 0.f;
    for (int d = 0; d < 256; ++d) {
        float v = zp[(size_t)d << 10];
        s += v * v;
    }
    zn[n] = s;
}

// ---------------- prep: split z (with transpose) ----------------
__global__ __launch_bounds__(256)
void split_z_kernel(const float* __restrict__ z,
                    unsigned short* __restrict__ zh, unsigned short* __restrict__ zl) {
    __shared__ float t[64][65];
    const int b = blockIdx.z, hw0 = blockIdx.x * 64, d0 = blockIdx.y * 64;
    const int c = threadIdx.x & 63, rg = threadIdx.x >> 6;
#pragma unroll
    for (int it = 0; it < 16; ++it) {
        int dl = it * 4 + rg;
        t[dl][c] = z[(size_t)b * 262144 + (size_t)(d0 + dl) * 1024 + hw0 + c];
    }
    __syncthreads();
#pragma unroll
    for (int it = 0; it < 16; ++it) {
        int nl = it * 4 + rg;
        float f = t[c][nl];
        unsigned short h = f2bf(f);
        unsigned short l = f2bf(f - bf2f(h));
        size_t o = (size_t)(b * 1024 + hw0 + nl) * 256 + d0 + c;
        zh[o] = h; zl[o] = l;
    }
}

// ---------------- prep: split codebook (layout preserved) ----------------
__global__ __launch_bounds__(256)
void split_c_kernel(const float* __restrict__ cb,
                    unsigned short* __restrict__ ch, unsigned short* __restrict__ cl) {
    int gid = blockIdx.x * 256 + threadIdx.x;     // float4 index; 8192*256/4 = 524288
    float4 v = ((const float4*)cb)[gid];
    ushort4 hv, lv;
    hv.x = f2bf(v.x); lv.x = f2bf(v.x - bf2f(hv.x));
    hv.y = f2bf(v.y); lv.y = f2bf(v.y - bf2f(hv.y));
    hv.z = f2bf(v.z); lv.z = f2bf(v.z - bf2f(hv.z));
    hv.w = f2bf(v.w); lv.w = f2bf(v.w - bf2f(hv.w));
    ((ushort4*)ch)[gid] = hv;
    ((ushort4*)cl)[gid] = lv;
}

// ---------------- screening GEMM + candidate collection ----------------
// 128x128 tile, BK=32, 4 waves (2x2), 16x16x32 bf16 MFMA, 3 MFMAs per frag-pair.
__global__ __launch_bounds__(256)
void gemm_screen(const unsigned short* __restrict__ zh, const unsigned short* __restrict__ zl,
                 const unsigned short* __restrict__ ch, const unsigned short* __restrict__ cl,
                 const float* __restrict__ zn,
                 unsigned* __restrict__ gmin, unsigned* __restrict__ cnt,
                 int* __restrict__ cand_i) {
    __shared__ char smem[32768];   // zh_s[0:8K) zl_s[8K:16K) ch_s[16K:24K) cl_s[24K:32K)
    const int tid = threadIdx.x;
    const int lane = tid & 63;
    const int wv = tid >> 6;
    const int wm = wv >> 1, wn = wv & 1;
    const int n0 = blockIdx.x * 128;
    const int k0 = blockIdx.y * 128;
    const int l15 = lane & 15, lh = lane >> 4;

    f32x4 acc[4][4];
#pragma unroll
    for (int i = 0; i < 4; ++i)
#pragma unroll
        for (int j = 0; j < 4; ++j) acc[i][j] = (f32x4){0.f, 0.f, 0.f, 0.f};

    for (int kt = 0; kt < 8; ++kt) {
        const int d0 = kt * 32;
        __syncthreads();   // prior step's LDS reads done
        // stage 4 arrays x 2 rounds; granule swizzle: s_phys = (s_log + (r>>1)) & 3
        // (2-way bank aliasing on ds_read_b128 -> free)
#pragma unroll
        for (int j = 0; j < 2; ++j) {
            int g = j * 256 + tid;
            int r = g >> 2;
            int sl = ((g & 3) - (r >> 1)) & 3;
            int lbase = j * 4096 + wv * 1024;   // HW adds lane*16
            size_t ga = (size_t)(n0 + r) * 256 + d0 + sl * 8;
            size_t gc = (size_t)(k0 + r) * 256 + d0 + sl * 8;
            gload_lds16(zh + ga, smem + 0 + lbase);
            gload_lds16(zl + ga, smem + 8192 + lbase);
            gload_lds16(ch + gc, smem + 16384 + lbase);
            gload_lds16(cl + gc, smem + 24576 + lbase);
        }
        __syncthreads();   // staged data visible
        bf16x8 ah[4], al[4], bh[4], bl[4];
#pragma unroll
        for (int mi = 0; mi < 4; ++mi) {
            int r = wm * 64 + mi * 16 + l15;
            int byte = r * 64 + ((((r >> 1) + lh) & 3) << 4);
            ah[mi] = *(const bf16x8*)(smem + 0 + byte);
            al[mi] = *(const bf16x8*)(smem + 8192 + byte);
        }
#pragma unroll
        for (int ni = 0; ni < 4; ++ni) {
            int r = wn * 64 + ni * 16 + l15;
            int byte = r * 64 + ((((r >> 1) + lh) & 3) << 4);
            bh[ni] = *(const bf16x8*)(smem + 16384 + byte);
            bl[ni] = *(const bf16x8*)(smem + 24576 + byte);
        }
#pragma unroll
        for (int mi = 0; mi < 4; ++mi)
#pragma unroll
            for (int ni = 0; ni < 4; ++ni) {
                acc[mi][ni] = __builtin_amdgcn_mfma_f32_16x16x32_bf16(ah[mi], bh[ni], acc[mi][ni], 0, 0, 0);
                acc[mi][ni] = __builtin_amdgcn_mfma_f32_16x16x32_bf16(ah[mi], bl[ni], acc[mi][ni], 0, 0, 0);
                acc[mi][ni] = __builtin_amdgcn_mfma_f32_16x16x32_bf16(al[mi], bh[ni], acc[mi][ni], 0, 0, 0);
            }
    }

    // epilogue: per row-group, block-local min -> atomicMin running global min,
    // append candidate indices within tau = gmin_now + margin
#pragma unroll
    for (int mi = 0; mi < 4; ++mi) {
#pragma unroll
        for (int reg = 0; reg < 4; ++reg) {
            int row = wm * 64 + mi * 16 + lh * 4 + reg;
            int n = n0 + row;
            float zz = zn[n];
            float margin = 2.0f * ulpf(zz) + 2e-6f;   // covers grid ulp + 2*screen_eps
            float s[4]; int kk[4];
#pragma unroll
            for (int ni = 0; ni < 4; ++ni) {
                kk[ni] = k0 + wn * 64 + ni * 16 + l15;
                s[ni] = zz - 2.0f * acc[mi][ni][reg];
            }
            float ls = s[0]; int li = kk[0];
#pragma unroll
            for (int ni = 1; ni < 4; ++ni)
                if (s[ni] < ls) { ls = s[ni]; li = kk[ni]; }   // kk ascending
#pragma unroll
            for (int m = 1; m <= 8; m <<= 1) {
                float ps = __shfl_xor(ls, m);
                int pi = __shfl_xor(li, m);
                if (ps < ls || (ps == ls && pi < li)) { ls = ps; li = pi; }
            }
            float tau = 0.f;
            if (l15 == 0) {
                unsigned key = __float_as_uint(ls);   // scores > 0 always (zz ~ 256 >> |2dot|)
                unsigned old = atomicMin(&gmin[n], key);
                float g = fminf(ls, __uint_as_float(old));
                tau = g + margin;
            }
            tau = __shfl(tau, lane & 48);
#pragma unroll
            for (int ni = 0; ni < 4; ++ni) {
                if (s[ni] <= tau) {
                    unsigned slot = atomicAdd(&cnt[n], 1u);
                    if (slot < CAP) cand_i[n * CAP + slot] = kk[ni];
                }
            }
        }
    }
}

// ---------------- exact rescore + final argmin ----------------
__global__ __launch_bounds__(256)
void select_kernel(const float* __restrict__ z, const float* __restrict__ cb,
                   const float* __restrict__ zn, const unsigned* __restrict__ cnt,
                   const int* __restrict__ cand_i,
                   int* __restrict__ codes, float* __restrict__ out_codes) {
    __shared__ float zrow_s[4][256];
    const int wv = threadIdx.x >> 6, lane = threadIdx.x & 63;
    const int n = blockIdx.x * 4 + wv;
    const int b = n >> 10, hw = n & 1023;
    const float* zp = z + (size_t)b * 262144 + hw;
#pragma unroll
    for (int t = 0; t < 4; ++t)
        zrow_s[wv][t * 64 + lane] = zp[(size_t)(t * 64 + lane) << 10];
    // same-wave LDS write->read: compiler inserts lgkmcnt wait
    const float zz = zn[n];
    const unsigned c = cnt[n];
    float bs; int bi;
    if (c > 0 && c <= CAP) {
        int myk = 0x7fffffff; float ss = 3.0e38f;
        if (lane < (int)c) {
            myk = cand_i[n * CAP + lane];
            const float* cr = cb + (size_t)myk * 256;
            float dot = 0.f;
            for (int d4 = 0; d4 < 64; ++d4) {       // exact sequential chain
                float4 cv = ((const float4*)cr)[d4];
                float4 zv = ((const float4*)&zrow_s[wv][0])[d4];
                dot = fmaf(zv.x, cv.x, dot);
                dot = fmaf(zv.y, cv.y, dot);
                dot = fmaf(zv.z, cv.z, dot);
                dot = fmaf(zv.w, cv.w, dot);
            }
            ss = zz - 2.0f * dot;
        }
        bs = ss; bi = myk;
    } else {
        // fallback: exact full scan, 4 parallel chains per lane for ILP
        bs = 3.0e38f; bi = 0x7fffffff;
        for (int j = 0; j < 128; j += 4) {
            const float* c0 = cb + (size_t)((j + 0) * 64 + lane) * 256;
            const float* c1 = cb + (size_t)((j + 1) * 64 + lane) * 256;
            const float* c2 = cb + (size_t)((j + 2) * 64 + lane) * 256;
            const float* c3 = cb + (size_t)((j + 3) * 64 + lane) * 256;
            float dA = 0.f, dB = 0.f, dC = 0.f, dD = 0.f;
            for (int d4 = 0; d4 < 64; ++d4) {
                float4 zv = ((const float4*)&zrow_s[wv][0])[d4];
                float4 v0 = ((const float4*)c0)[d4];
                float4 v1 = ((const float4*)c1)[d4];
                float4 v2 = ((const float4*)c2)[d4];
                float4 v3 = ((const float4*)c3)[d4];
                dA = fmaf(zv.x, v0.x, dA); dA = fmaf(zv.y, v0.y, dA); dA = fmaf(zv.z, v0.z, dA); dA = fmaf(zv.w, v0.w, dA);
                dB = fmaf(zv.x, v1.x, dB); dB = fmaf(zv.y, v1.y, dB); dB = fmaf(zv.z, v1.z, dB); dB = fmaf(zv.w, v1.w, dB);
                dC = fmaf(zv.x, v2.x, dC); dC = fmaf(zv.y, v2.y, dC); dC = fmaf(zv.z, v2.z, dC); dC = fmaf(zv.w, v2.w, dC);
                dD = fmaf(zv.x, v3.x, dD); dD = fmaf(zv.y, v3.y, dD); dD = fmaf(zv.z, v3.z, dD); dD = fmaf(zv.w, v3.w, dD);
            }
            float sA = zz - 2.0f * dA, sB = zz - 2.0f * dB, sC = zz - 2.0f * dC, sD = zz - 2.0f * dD;
            int kA = (j + 0) * 64 + lane, kB = (j + 1) * 64 + lane, kC = (j + 2) * 64 + lane, kD = (j + 3) * 64 + lane;
            if (sA < bs) { bs = sA; bi = kA; }
            if (sB < bs) { bs = sB; bi = kB; }
            if (sC < bs) { bs = sC; bi = kC; }
            if (sD < bs) { bs = sD; bi = kD; }
        }
    }
#pragma unroll
    for (int m = 1; m <= 32; m <<= 1) {
        float ps = __shfl_xor(bs, m);
        int pi = __shfl_xor(bi, m);
        if (ps < bs || (ps == bs && pi < bi)) { bs = ps; bi = pi; }
    }
    if (lane == 0) { codes[n] = bi; out_codes[n] = (float)bi; }
}

// ---------------- finalize: z_q gather + loss ----------------
__global__ __launch_bounds__(256)
void finalize2_kernel(const float* __restrict__ z, const float* __restrict__ cb,
                      const int* __restrict__ codes, float* __restrict__ out) {
    __shared__ int codes_s[64];
    __shared__ float wsum[4];
    const int nbase = blockIdx.x * 64;
    const int tid = threadIdx.x;
    if (tid < 64) codes_s[tid] = codes[nbase + tid];
    __syncthreads();
    const int lane = tid & 63;
    const int w = tid >> 6;
    const int n = nbase + lane;
    const int b = n >> 10, hw = n & 1023;
    const int code = codes_s[lane];
    const float* crow = cb + (size_t)code * 256;
    const float* zrow = z + (size_t)b * 262144 + hw;
    float* orow = out + (size_t)b * 262144 + hw;
    float part = 0.f;
    for (int j = 0; j < 64; ++j) {
        int d = w * 64 + j;
        float cv = crow[d];
        float ze = zrow[(size_t)d * 1024];
        orow[(size_t)d * 1024] = cv;
        float diff = ze - cv;
        part += diff * diff;
    }
#pragma unroll
    for (int off = 32; off > 0; off >>= 1) part += __shfl_down(part, off);
    if (lane == 0) wsum[w] = part;
    __syncthreads();
    if (tid == 0) {
        float t = (wsum[0] + wsum[1] + wsum[2] + wsum[3]) * (1.25f / 4194304.f);
        atomicAdd(out + 4194304, t);
    }
}

// ================= fallback path (round-2 kernels, ws-small case) =================
#define NT 128
#define KT 128
#define DC 64
#define KS 4
#define KRANGE (8192 / KS)
#define PSCORE_OFF 16384
#define PIDX_OFF (16384 + KS * 16384)

__global__ __launch_bounds__(256, 2)
void dist_argmin_kernel(const float* __restrict__ z, const float* __restrict__ cb,
                        const float* __restrict__ zn,
                        float* __restrict__ pscore, int* __restrict__ pidx) {
    __shared__ float zs[DC][NT];
    __shared__ float cs[DC][KT];
    const int tid = threadIdx.x;
    const int tn = tid & 15;
    const int tk = tid >> 4;
    const int n0 = blockIdx.x * NT;
    const int b = n0 >> 10;
    const int hw0 = n0 & 1023;
    const float* zb = z + (size_t)b * 262144 + hw0;
    const int k0base = blockIdx.y * KRANGE;
    float zzr[8];
#pragma unroll
    for (int i = 0; i < 8; ++i) {
        int row = (i < 4) ? (tn * 4 + i) : (64 + tn * 4 + (i - 4));
        zzr[i] = zn[n0 + row];
    }
    float best[8]; int bidx[8];
#pragma unroll
    for (int i = 0; i < 8; ++i) { best[i] = 3.0e38f; bidx[i] = 0; }
    for (int kt = 0; kt < KRANGE / KT; ++kt) {
        const int k0 = k0base + kt * KT;
        float acc[8][8];
#pragma unroll
        for (int i = 0; i < 8; ++i)
#pragma unroll
            for (int j = 0; j < 8; ++j) acc[i][j] = 0.f;
        for (int dc = 0; dc < 256; dc += DC) {
            __syncthreads();
#pragma unroll
            for (int it = 0; it < 8; ++it) {
                int idx = it * 256 + tid;
                int d = idx >> 5, nv = idx & 31;
                float4 v = *(const float4*)(zb + (size_t)(dc + d) * 1024 + nv * 4);
                *(float4*)&zs[d][nv * 4] = v;
            }
#pragma unroll
            for (int it = 0; it < 8; ++it) {
                int idx = it * 256 + tid;
                int k = idx >> 4, dv = idx & 15;
                float4 v = *(const float4*)(cb + (size_t)(k0 + k) * 256 + dc + dv * 4);
                int colv = k ^ ((dv & 7) << 2);
                cs[dv * 4 + 0][colv] = v.x;
                cs[dv * 4 + 1][colv] = v.y;
                cs[dv * 4 + 2][colv] = v.z;
                cs[dv * 4 + 3][colv] = v.w;
            }
            __syncthreads();
#pragma unroll 2
            for (int d = 0; d < DC; ++d) {
                int swz = ((d >> 2) & 7) << 2;
                float4 a0 = *(const float4*)&zs[d][tn * 4];
                float4 a1 = *(const float4*)&zs[d][64 + tn * 4];
                float4 b0 = *(const float4*)&cs[d][(tk * 4) ^ swz];
                float4 b1 = *(const float4*)&cs[d][(64 + tk * 4) ^ swz];
                float av[8] = {a0.x, a0.y, a0.z, a0.w, a1.x, a1.y, a1.z, a1.w};
                float bv[8] = {b0.x, b0.y, b0.z, b0.w, b1.x, b1.y, b1.z, b1.w};
#pragma unroll
                for (int i = 0; i < 8; ++i)
#pragma unroll
                    for (int j = 0; j < 8; ++j)
                        acc[i][j] = fmaf(av[i], bv[j], acc[i][j]);
            }
        }
#pragma unroll
        for (int j = 0; j < 8; ++j) {
            int kloc = (j < 4) ? (tk * 4 + j) : (64 + tk * 4 + (j - 4));
            int kk = k0 + kloc;
#pragma unroll
            for (int i = 0; i < 8; ++i) {
                float s = zzr[i] - 2.0f * acc[i][j];
                if (s < best[i]) { best[i] = s; bidx[i] = kk; }
            }
        }
    }
    __syncthreads();
    float* sredf = &zs[0][0];
    int* sredi = (int*)&cs[0][0];
#pragma unroll
    for (int i = 0; i < 8; ++i) {
        int row = (i < 4) ? (tn * 4 + i) : (64 + tn * 4 + (i - 4));
        sredf[row * 16 + tk] = best[i];
        sredi[row * 16 + tk] = bidx[i];
    }
    __syncthreads();
    if (tid < NT) {
        float bs = sredf[tid * 16];
        int bi = sredi[tid * 16];
#pragma unroll
        for (int t = 1; t < 16; ++t) {
            float s = sredf[tid * 16 + t];
            int ix = sredi[tid * 16 + t];
            if (s < bs || (s == bs && ix < bi)) { bs = s; bi = ix; }
        }
        pscore[blockIdx.y * 16384 + n0 + tid] = bs;
        pidx[blockIdx.y * 16384 + n0 + tid] = bi;
    }
}

__global__ __launch_bounds__(256)
void finalize_kernel(const float* __restrict__ z, const float* __restrict__ cb,
                     const float* __restrict__ pscore, const int* __restrict__ pidx,
                     float* __restrict__ out) {
    __shared__ int codes_s[64];
    __shared__ float wsum[4];
    const int nbase = blockIdx.x * 64;
    const int tid = threadIdx.x;
    if (tid < 64) {
        int n = nbase + tid;
        float bs = pscore[n];
        int bi = pidx[n];
#pragma unroll
        for (int p = 1; p < KS; ++p) {
            float s = pscore[p * 16384 + n];
            int ix = pidx[p * 16384 + n];
            if (s < bs || (s == bs && ix < bi)) { bs = s; bi = ix; }
        }
        codes_s[tid] = bi;
        out[4194305 + n] = (float)bi;
    }
    __syncthreads();
    const int lane = tid & 63;
    const int w = tid >> 6;
    const int n = nbase + lane;
    const int b = n >> 10, hw = n & 1023;
    const int code = codes_s[lane];
    const float* crow = cb + (size_t)code * 256;
    const float* zrow = z + (size_t)b * 262144 + hw;
    float* orow = out + (size_t)b * 262144 + hw;
    float part = 0.f;
    for (int j = 0; j < 64; ++j) {
        int d = w * 64 + j;
        float cv = crow[d];
        float ze = zrow[(size_t)d * 1024];
        orow[(size_t)d * 1024] = cv;
        float diff = ze - cv;
        part += diff * diff;
    }
#pragma unroll
    for (int off = 32; off > 0; off >>= 1) part += __shfl_down(part, off);
    if (lane == 0) wsum[w] = part;
    __syncthreads();
    if (tid == 0) {
        float t = (wsum[0] + wsum[1] + wsum[2] + wsum[3]) * (1.25f / 4194304.f);
        atomicAdd(out + 4194304, t);
    }
}

// ================= launcher =================
extern "C" void kernel_launch(void* const* d_in, const int* in_sizes, int n_in,
                              void* d_out, int out_size, void* d_ws, size_t ws_size,
                              hipStream_t stream) {
    const float* z = (const float*)d_in[0];
    const float* cb = (const float*)d_in[1];
    float* out = (float*)d_out;
    char* wsb = (char*)d_ws;

    if (ws_size >= WS_NEED) {
        float* zn = (float*)(wsb + ZN_B);
        int* codes = (int*)(wsb + CODES_B);
        unsigned* gmin = (unsigned*)(wsb + GMIN_B);
        unsigned* cnt = (unsigned*)(wsb + CNT_B);
        int* cand_i = (int*)(wsb + CANDI_B);
        unsigned short* zh = (unsigned short*)(wsb + ZH_B);
        unsigned short* zl = (unsigned short*)(wsb + ZL_B);
        unsigned short* ch = (unsigned short*)(wsb + CH_B);
        unsigned short* cl = (unsigned short*)(wsb + CL_B);

        hipMemsetAsync(wsb + GMIN_B, 0xFF, 65536, stream);   // gmin = +max
        hipMemsetAsync(wsb + CNT_B, 0, 65536, stream);
        hipMemsetAsync(out + 4194304, 0, sizeof(float), stream);

        znorm_kernel<<<64, 256, 0, stream>>>(z, zn);
        split_z_kernel<<<dim3(16, 4, 16), 256, 0, stream>>>(z, zh, zl);
        split_c_kernel<<<2048, 256, 0, stream>>>(cb, ch, cl);
        gemm_screen<<<dim3(128, 64), 256, 0, stream>>>(zh, zl, ch, cl, zn, gmin, cnt, cand_i);
        select_kernel<<<4096, 256, 0, stream>>>(z, cb, zn, cnt, cand_i, codes, out + 4194305);
        finalize2_kernel<<<256, 256, 0, stream>>>(z, cb, codes, out);
    } else {
        float* zn = (float*)wsb;
        float* pscore = (float*)wsb + PSCORE_OFF;
        int* pidx = (int*)((float*)wsb + PIDX_OFF);
        znorm_kernel<<<64, 256, 0, stream>>>(z, zn);
        dim3 grid(16384 / NT, KS);
        dist_argmin_kernel<<<grid, 256, 0, stream>>>(z, cb, zn, pscore, pidx);
        hipMemsetAsync(out + 4194304, 0, sizeof(float), stream);
        finalize_kernel<<<16384 / 64, 256, 0, stream>>>(z, cb, pscore, pidx, out);
    }
}